// Round 8
// baseline (307.218 us; speedup 1.0000x reference)
//
#include <hip/hip_runtime.h>

// ---------------------------------------------------------------------------
// Fused attention block: qkv = x@Wqkv+b; per-head softmax(q k^T/8 + keybias) v;
// out = attn@Wproj+b.  B=4 N=2048 C=768 H=12 HD=64.
// Internal compute bf16 MFMA (16x16x32), fp32 accumulate.
// R8: attn occupancy/latency restructure — 16 q-rows per wave (grid 1536,
// ~16 waves/CU), V+eb global-direct to registers issued early (T14/m169),
// K-only LDS double-buffer (16KB) with 1 barrier/iter.
// Keeps: swapped QK^T + kappa1 (in-register P), eb-folded bias, shift-free
// softmax, XOR-swizzled K LDS, no setprio.
// ---------------------------------------------------------------------------

typedef short short8 __attribute__((ext_vector_type(8)));
typedef float f32x4 __attribute__((ext_vector_type(4)));
typedef unsigned int u32x4 __attribute__((ext_vector_type(4)));

#define GLB_AS(p) ((const __attribute__((address_space(1))) void*)(p))
#define LDS_AS(p) ((__attribute__((address_space(3))) void*)(p))

__device__ __forceinline__ void gload_lds16(const void* g, void* l) {
  // dest = wave-uniform LDS base + lane*16 (m97 fast path)
  __builtin_amdgcn_global_load_lds(GLB_AS(g), LDS_AS(l), 16, 0, 0);
}

__device__ __forceinline__ f32x4 mfma16(short8 a, short8 b, f32x4 c) {
  return __builtin_amdgcn_mfma_f32_16x16x32_bf16(a, b, c, 0, 0, 0);
}

__device__ __forceinline__ unsigned short f2bf(float f) {
  union { float f; unsigned u; } v; v.f = f;
  unsigned r = v.u + 0x7fffu + ((v.u >> 16) & 1u);
  return (unsigned short)(r >> 16);
}

__device__ __forceinline__ float bf2f(unsigned short u) {
  union { unsigned u; float f; } v; v.u = ((unsigned)u) << 16;
  return v.f;
}

// packed f32x2 -> bf16x2 (lo = a, hi = b)
__device__ __forceinline__ unsigned cvt_pk_bf16(float a, float b) {
  unsigned r;
  asm("v_cvt_pk_bf16_f32 %0, %1, %2" : "=v"(r) : "v"(a), "v"(b));
  return r;
}

#define LOG2E 1.44269504088896340736f

// key-slot permutation: S^T slot m holds original key kappa1(m).
// kappa1(m) = 32*m4 + 8*((m>>2)&3) + 4*m5 + (m&3)  (bijective on 0..63)
__device__ __forceinline__ int kappa1(int m) {
  return ((m >> 4) & 1) * 32 + ((m >> 2) & 3) * 8 + ((m >> 5) & 1) * 4 + (m & 3);
}

// --------------------------- pre-pass kernels ------------------------------

__global__ __launch_bounds__(256) void cvt_f32_bf16(const float* __restrict__ in,
                                                    unsigned short* __restrict__ out,
                                                    int n8) {
  int i = blockIdx.x * 256 + threadIdx.x;
  if (i >= n8) return;
  const float4* p = (const float4*)in + 2 * (size_t)i;
  float4 a = p[0], c = p[1];
  short8 r;
  r[0] = (short)f2bf(a.x); r[1] = (short)f2bf(a.y); r[2] = (short)f2bf(a.z); r[3] = (short)f2bf(a.w);
  r[4] = (short)f2bf(c.x); r[5] = (short)f2bf(c.y); r[6] = (short)f2bf(c.z); r[7] = (short)f2bf(c.w);
  ((short8*)out)[i] = r;
}

// ebb[i] = bf16(exp(klb[i]))  (natural key order)
__global__ __launch_bounds__(256) void exp_bias(const float* __restrict__ in,
                                                unsigned short* __restrict__ out, int n) {
  int i = blockIdx.x * 256 + threadIdx.x;
  if (i < n) out[i] = f2bf(__builtin_exp2f(in[i] * LOG2E));
}

// transpose + convert: src fp32 [R][C] -> dst bf16 [C][R]
__global__ __launch_bounds__(256) void tr_cvt_f32_bf16(const float* __restrict__ src,
                                                       unsigned short* __restrict__ dst,
                                                       int R, int C) {
  __shared__ float t[32][33];
  int tx = threadIdx.x & 31, ty = threadIdx.x >> 5;
  int c0 = blockIdx.x * 32, r0 = blockIdx.y * 32;
#pragma unroll
  for (int i = 0; i < 32; i += 8)
    t[ty + i][tx] = src[(size_t)(r0 + ty + i) * C + c0 + tx];
  __syncthreads();
#pragma unroll
  for (int i = 0; i < 32; i += 8)
    dst[(size_t)(c0 + ty + i) * R + r0 + tx] = f2bf(t[tx][ty + i]);
}

// per-head bf16 transpose + eb-scale: src [48][2048][64] -> dst [48][64][2048],
// dst[.][d][n] = src[.][n][d] * eb[b][n]   (bias folded into V)
__global__ __launch_bounds__(256) void tr_bf16_head(const unsigned short* __restrict__ src,
                                                    const unsigned short* __restrict__ ebb,
                                                    unsigned short* __restrict__ dst) {
  __shared__ unsigned short t[32][33];
  int tx = threadIdx.x & 31, ty = threadIdx.x >> 5;
  size_t hb = (size_t)blockIdx.z * (2048 * 64);
  int b = blockIdx.z / 12;
  int c0 = blockIdx.x * 32, r0 = blockIdx.y * 32;
#pragma unroll
  for (int i = 0; i < 32; i += 8)
    t[ty + i][tx] = src[hb + (size_t)(r0 + ty + i) * 64 + c0 + tx];
  __syncthreads();
  float eb = bf2f(ebb[b * 2048 + r0 + tx]);
#pragma unroll
  for (int i = 0; i < 32; i += 8)
    dst[hb + (size_t)(c0 + ty + i) * 2048 + r0 + tx] = f2bf(bf2f(t[tx][ty + i]) * eb);
}

// ------------------------------- GEMM --------------------------------------
// C[M,N] = A[M,K] * Bt[N,K]^T, 128x128 tile, BK=64, 4 waves (2x2), m97 structure.
// EPI=0: qkv epilogue (bias, q-scale incl. log2e, scatter to q/k/v [B,H,N,64])
// EPI=1: proj epilogue (bias, fp32 out [M][768])
template <int EPI>
__global__ __launch_bounds__(256, 2) void gemm_bt(
    const unsigned short* __restrict__ A, const unsigned short* __restrict__ Bt,
    const float* __restrict__ bias, float* __restrict__ outf,
    unsigned short* __restrict__ qo, unsigned short* __restrict__ ko,
    unsigned short* __restrict__ vo, int K) {
  __shared__ __align__(16) unsigned short As[128 * 64];
  __shared__ __align__(16) unsigned short Bs[128 * 64];
  const int tid = threadIdx.x;
  const int lane = tid & 63, wid = tid >> 6;
  const int lr = lane & 15, lg = lane >> 4;
  const int bm = blockIdx.x, bn = blockIdx.y;
  const int wr = (wid >> 1) * 64, wc = (wid & 1) * 64;

  const unsigned short* ap[4];
  const unsigned short* bp[4];
  unsigned loff[4];
#pragma unroll
  for (int i = 0; i < 4; ++i) {
    int c = wid * 4 + i;
    int r = c * 8 + (lane >> 3);
    int gs = (lane & 7) ^ (r & 7);
    ap[i] = A + (size_t)(bm * 128 + r) * K + gs * 8;
    bp[i] = Bt + (size_t)(bn * 128 + r) * K + gs * 8;
    loff[i] = (unsigned)c * 1024;
  }

  f32x4 acc[4][4] = {};
  const int nt = K >> 6;
  for (int t = 0; t < nt; ++t) {
#pragma unroll
    for (int i = 0; i < 4; ++i) {
      gload_lds16(ap[i], (char*)As + loff[i]);
      gload_lds16(bp[i], (char*)Bs + loff[i]);
      ap[i] += 64;
      bp[i] += 64;
    }
    __syncthreads();
#pragma unroll
    for (int kkk = 0; kkk < 2; ++kkk) {
      short8 af[4], bf[4];
#pragma unroll
      for (int mf = 0; mf < 4; ++mf) {
        int r = wr + mf * 16 + lr;
        int g = kkk * 4 + lg;
        af[mf] = *(const short8*)((const char*)As + r * 128 + ((g ^ (r & 7)) << 4));
      }
#pragma unroll
      for (int nf = 0; nf < 4; ++nf) {
        int r = wc + nf * 16 + lr;
        int g = kkk * 4 + lg;
        bf[nf] = *(const short8*)((const char*)Bs + r * 128 + ((g ^ (r & 7)) << 4));
      }
#pragma unroll
      for (int mf = 0; mf < 4; ++mf)
#pragma unroll
        for (int nf = 0; nf < 4; ++nf)
          acc[mf][nf] = mfma16(af[mf], bf[nf], acc[mf][nf]);
    }
    __syncthreads();
  }

  const int colbase = bn * 128 + wc;
  float bv[4];
#pragma unroll
  for (int nf = 0; nf < 4; ++nf) bv[nf] = bias[colbase + nf * 16 + lr];

  if constexpr (EPI == 0) {
#pragma unroll
    for (int nf = 0; nf < 4; ++nf) {
      int col = colbase + nf * 16 + lr;
      int which = col / 768;
      int rem = col - which * 768;
      int h = rem >> 6, d = rem & 63;
#pragma unroll
      for (int mf = 0; mf < 4; ++mf) {
#pragma unroll
        for (int j = 0; j < 4; ++j) {
          int row = bm * 128 + wr + mf * 16 + lg * 4 + j;
          int bb = row >> 11, nn = row & 2047;
          float v = acc[mf][nf][j] + bv[nf];
          size_t off = (((size_t)bb * 12 + h) * 2048 + nn) * 64 + d;
          if (which == 0)
            qo[off] = f2bf(v * (0.125f * LOG2E));  // fold 1/sqrt(64) and log2e into Q
          else if (which == 1)
            ko[off] = f2bf(v);
          else
            vo[off] = f2bf(v);
        }
      }
    }
  } else {
#pragma unroll
    for (int mf = 0; mf < 4; ++mf) {
#pragma unroll
      for (int j = 0; j < 4; ++j) {
        int row = bm * 128 + wr + mf * 16 + lg * 4 + j;
#pragma unroll
        for (int nf = 0; nf < 4; ++nf) {
          int col = colbase + nf * 16 + lr;
          outf[(size_t)row * 768 + col] = acc[mf][nf][j] + bv[nf];
        }
      }
    }
  }
}

// --------------------------- flash attention -------------------------------
// grid (32 qblocks, 48 heads), 256 thr. Per block: 64 q-rows, 4 waves x 16 rows.
// K: LDS dbuf (16KB), kappa1-permuted rows, XOR-swizzled, 1 barrier/iter.
// V + eb: global-direct to registers, issued at top of body (QK+exp2 phase
// covers L2 latency). P packed in-register (kappa1). Shift-free softmax.
__global__ __launch_bounds__(256, 4) void attn_fused(
    const unsigned short* __restrict__ Q, const unsigned short* __restrict__ Kx,
    const unsigned short* __restrict__ Vt, const unsigned short* __restrict__ ebb,
    unsigned short* __restrict__ Ao) {
  __shared__ __align__(16) unsigned short Ks[2][64 * 64];
  const int tid = threadIdx.x, lane = tid & 63, wid = tid >> 6;
  const int lr = lane & 15, lg = lane >> 4;
  const int qb = blockIdx.x, bh = blockIdx.y;
  const int b = bh / 12, h = bh - b * 12;
  const size_t hoff = (size_t)bh * (2048 * 64);
  const unsigned short* Qh = Q + hoff;
  const unsigned short* Kh = Kx + hoff;
  const unsigned short* Vh = Vt + hoff;        // [64][2048], pre-scaled by eb
  const unsigned short* ebh = ebb + b * 2048;  // bf16 exp(bias), natural order

  // Q fragments (16 q-rows per wave, held whole kernel)
  short8 qf[2];
#pragma unroll
  for (int kkk = 0; kkk < 2; ++kkk) {
    int qr = qb * 64 + wid * 16 + lr;
    qf[kkk] = *(const short8*)(Qh + (size_t)qr * 64 + kkk * 32 + lg * 8);
  }

  // K staging: 8 chunks of 1KB per tile; wave w covers chunks w*2, w*2+1.
  const int c0 = wid * 2, c1 = wid * 2 + 1;
  const int r0s = c0 * 8 + (lane >> 3), r1s = c1 * 8 + (lane >> 3);
  const int g0 = (lane & 7) ^ (r0s & 7), g1 = (lane & 7) ^ (r1s & 7);
  const int k1r0 = kappa1(r0s), k1r1 = kappa1(r1s);

  // V per-lane row pointers (col advances by 64 keys/tile)
  const unsigned short* vp[4];
#pragma unroll
  for (int nf = 0; nf < 4; ++nf)
    vp[nf] = Vh + (size_t)(nf * 16 + lr) * 2048 + lg * 8;

  f32x4 o[4] = {};
  f32x4 ol = {};  // l accumulator via MFMA (all cols identical)

#define STAGE_K(buf, t)                                                                \
  do {                                                                                 \
    const int kt0_ = (t) * 64;                                                         \
    gload_lds16(Kh + (size_t)(kt0_ + k1r0) * 64 + g0 * 8, (char*)Ks[buf] + c0 * 1024); \
    gload_lds16(Kh + (size_t)(kt0_ + k1r1) * 64 + g1 * 8, (char*)Ks[buf] + c1 * 1024); \
  } while (0)

  STAGE_K(0, 0);
  int cur = 0;

  for (int t = 0; t < 32; ++t) {
    __syncthreads();  // drains vmcnt: K[cur] landed; all waves done with K[cur^1]
    if (t + 1 < 32) STAGE_K(cur ^ 1, t + 1);

    const int kt0 = t * 64;

    // issue V + eb loads EARLY (global-direct; QK+exp2 phase hides latency)
    short8 vr[4][2];
#pragma unroll
    for (int nf = 0; nf < 4; ++nf)
#pragma unroll
      for (int kkk = 0; kkk < 2; ++kkk)
        vr[nf][kkk] = *(const short8*)(vp[nf] + kt0 + kkk * 32);
    short8 ebf[2];
#pragma unroll
    for (int kkk = 0; kkk < 2; ++kkk)
      ebf[kkk] = *(const short8*)(ebh + kt0 + kkk * 32 + lg * 8);

    // S^T = K_slot Q^T : s[nf]
    f32x4 s[4] = {};
#pragma unroll
    for (int kkk = 0; kkk < 2; ++kkk) {
      short8 kf[4];
#pragma unroll
      for (int nf = 0; nf < 4; ++nf) {
        int r = nf * 16 + lr, g = kkk * 4 + lg;
        kf[nf] = *(const short8*)((const char*)Ks[cur] + r * 128 + ((g ^ (r & 7)) << 4));
      }
#pragma unroll
      for (int nf = 0; nf < 4; ++nf)
        s[nf] = mfma16(kf[nf], qf[kkk], s[nf]);
    }

    // p = exp2(s); shift-free; bias lives in V/eb
#pragma unroll
    for (int nf = 0; nf < 4; ++nf)
#pragma unroll
      for (int j = 0; j < 4; ++j)
        s[nf][j] = __builtin_exp2f(s[nf][j]);

    // pack PV A-fragments in-register (kappa1 lines the slots up)
    short8 pa[2];
#pragma unroll
    for (int kkk = 0; kkk < 2; ++kkk) {
      u32x4 w;
      w[0] = cvt_pk_bf16(s[kkk][0], s[kkk][1]);
      w[1] = cvt_pk_bf16(s[kkk][2], s[kkk][3]);
      w[2] = cvt_pk_bf16(s[kkk + 2][0], s[kkk + 2][1]);
      w[3] = cvt_pk_bf16(s[kkk + 2][2], s[kkk + 2][3]);
      pa[kkk] = __builtin_bit_cast(short8, w);
    }

    // O += P (eb*V) ; l += P @ eb
#pragma unroll
    for (int kkk = 0; kkk < 2; ++kkk) {
      ol = mfma16(pa[kkk], ebf[kkk], ol);
#pragma unroll
      for (int nf = 0; nf < 4; ++nf)
        o[nf] = mfma16(pa[kkk], vr[nf][kkk], o[nf]);
    }
    cur ^= 1;
  }
#undef STAGE_K

  // epilogue: O / l -> bf16 -> attn_out [B][N][C]; l is in O-frag layout.
#pragma unroll
  for (int j = 0; j < 4; ++j) {
    float inv = 1.f / ol[j];
    int qr = qb * 64 + wid * 16 + lg * 4 + j;
#pragma unroll
    for (int nf = 0; nf < 4; ++nf) {
      int d = nf * 16 + lr;
      Ao[((size_t)b * 2048 + qr) * 768 + h * 64 + d] = f2bf(o[nf][j] * inv);
    }
  }
}

// ------------------------------ launcher -----------------------------------

extern "C" void kernel_launch(void* const* d_in, const int* in_sizes, int n_in,
                              void* d_out, int out_size, void* d_ws, size_t ws_size,
                              hipStream_t stream) {
  (void)in_sizes; (void)n_in; (void)out_size; (void)ws_size;
  const float* x = (const float*)d_in[0];
  const float* wqkv = (const float*)d_in[1];
  const float* bqkv = (const float*)d_in[2];
  const float* wproj = (const float*)d_in[3];
  const float* bproj = (const float*)d_in[4];
  const float* klb = (const float*)d_in[5];
  float* out = (float*)d_out;
  char* ws = (char*)d_ws;

  const size_t SZ = (size_t)8192 * 768 * 2;  // 12,582,912 B (one [B,N,C] bf16)
  unsigned short* xb = (unsigned short*)(ws);
  unsigned short* wqkvT = (unsigned short*)(ws + SZ);
  unsigned short* wprojT = (unsigned short*)(ws + SZ + 3538944);
  unsigned short* qbuf = (unsigned short*)(ws + SZ + 3538944 + 1179648);
  unsigned short* kbuf = (unsigned short*)(ws + SZ + 3538944 + 1179648 + SZ);
  unsigned short* vbuf = (unsigned short*)(ws + SZ + 3538944 + 1179648 + 2 * SZ);
  unsigned short* vtbuf = (unsigned short*)(ws + SZ + 3538944 + 1179648 + 3 * SZ);
  unsigned short* ebb = (unsigned short*)(ws + SZ + 3538944 + 1179648 + 4 * SZ);
  unsigned short* aob = xb;  // xb dead after gemm1; reuse for attention output

  cvt_f32_bf16<<<dim3(3072), dim3(256), 0, stream>>>(x, xb, 786432);
  exp_bias<<<dim3(32), dim3(256), 0, stream>>>(klb, ebb, 8192);
  tr_cvt_f32_bf16<<<dim3(72, 24), dim3(256), 0, stream>>>(wqkv, wqkvT, 768, 2304);
  tr_cvt_f32_bf16<<<dim3(24, 24), dim3(256), 0, stream>>>(wproj, wprojT, 768, 768);
  gemm_bt<0><<<dim3(64, 18), dim3(256), 0, stream>>>(xb, wqkvT, bqkv, nullptr,
                                                     qbuf, kbuf, vbuf, 768);
  tr_bf16_head<<<dim3(2, 64, 48), dim3(256), 0, stream>>>(vbuf, ebb, vtbuf);
  attn_fused<<<dim3(32, 48), dim3(256), 0, stream>>>(qbuf, kbuf, vtbuf, ebb, aob);
  gemm_bt<1><<<dim3(64, 6), dim3(256), 0, stream>>>(aob, wprojT, bproj, out,
                                                    nullptr, nullptr, nullptr, 768);
}

// Round 9
// 258.431 us; speedup vs baseline: 1.1888x; 1.1888x over previous
//
#include <hip/hip_runtime.h>

// ---------------------------------------------------------------------------
// Fused attention block: qkv = x@Wqkv+b; per-head softmax(q k^T/8 + keybias) v;
// out = attn@Wproj+b.  B=4 N=2048 C=768 H=12 HD=64.
// Internal compute bf16 MFMA (16x16x32), fp32 accumulate.
// R9: R7 compute structure EXACTLY (32 q-rows/wave, grid 16x48, swapped QK^T
// + kappa1 in-register P, eb-folded bias, shift-free softmax), but K/V/eb all
// global-direct to registers: ZERO LDS, ZERO barriers in the loop. Waves are
// fully independent; compiler pipelines loads across tiles (counted vmcnt).
// kappa1 applied via direct row addressing (bit-permutation, per-lane const).
// No setprio.
// ---------------------------------------------------------------------------

typedef short short8 __attribute__((ext_vector_type(8)));
typedef float f32x4 __attribute__((ext_vector_type(4)));
typedef unsigned int u32x4 __attribute__((ext_vector_type(4)));

#define GLB_AS(p) ((const __attribute__((address_space(1))) void*)(p))
#define LDS_AS(p) ((__attribute__((address_space(3))) void*)(p))

__device__ __forceinline__ void gload_lds16(const void* g, void* l) {
  // dest = wave-uniform LDS base + lane*16 (m97 fast path)
  __builtin_amdgcn_global_load_lds(GLB_AS(g), LDS_AS(l), 16, 0, 0);
}

__device__ __forceinline__ f32x4 mfma16(short8 a, short8 b, f32x4 c) {
  return __builtin_amdgcn_mfma_f32_16x16x32_bf16(a, b, c, 0, 0, 0);
}

__device__ __forceinline__ unsigned short f2bf(float f) {
  union { float f; unsigned u; } v; v.f = f;
  unsigned r = v.u + 0x7fffu + ((v.u >> 16) & 1u);
  return (unsigned short)(r >> 16);
}

__device__ __forceinline__ float bf2f(unsigned short u) {
  union { unsigned u; float f; } v; v.u = ((unsigned)u) << 16;
  return v.f;
}

// packed f32x2 -> bf16x2 (lo = a, hi = b)
__device__ __forceinline__ unsigned cvt_pk_bf16(float a, float b) {
  unsigned r;
  asm("v_cvt_pk_bf16_f32 %0, %1, %2" : "=v"(r) : "v"(a), "v"(b));
  return r;
}

#define LOG2E 1.44269504088896340736f

// --------------------------- pre-pass kernels ------------------------------

__global__ __launch_bounds__(256) void cvt_f32_bf16(const float* __restrict__ in,
                                                    unsigned short* __restrict__ out,
                                                    int n8) {
  int i = blockIdx.x * 256 + threadIdx.x;
  if (i >= n8) return;
  const float4* p = (const float4*)in + 2 * (size_t)i;
  float4 a = p[0], c = p[1];
  short8 r;
  r[0] = (short)f2bf(a.x); r[1] = (short)f2bf(a.y); r[2] = (short)f2bf(a.z); r[3] = (short)f2bf(a.w);
  r[4] = (short)f2bf(c.x); r[5] = (short)f2bf(c.y); r[6] = (short)f2bf(c.z); r[7] = (short)f2bf(c.w);
  ((short8*)out)[i] = r;
}

// ebb[i] = bf16(exp(klb[i]))  (natural key order)
__global__ __launch_bounds__(256) void exp_bias(const float* __restrict__ in,
                                                unsigned short* __restrict__ out, int n) {
  int i = blockIdx.x * 256 + threadIdx.x;
  if (i < n) out[i] = f2bf(__builtin_exp2f(in[i] * LOG2E));
}

// transpose + convert: src fp32 [R][C] -> dst bf16 [C][R]
__global__ __launch_bounds__(256) void tr_cvt_f32_bf16(const float* __restrict__ src,
                                                       unsigned short* __restrict__ dst,
                                                       int R, int C) {
  __shared__ float t[32][33];
  int tx = threadIdx.x & 31, ty = threadIdx.x >> 5;
  int c0 = blockIdx.x * 32, r0 = blockIdx.y * 32;
#pragma unroll
  for (int i = 0; i < 32; i += 8)
    t[ty + i][tx] = src[(size_t)(r0 + ty + i) * C + c0 + tx];
  __syncthreads();
#pragma unroll
  for (int i = 0; i < 32; i += 8)
    dst[(size_t)(c0 + ty + i) * R + r0 + tx] = f2bf(t[tx][ty + i]);
}

// per-head bf16 transpose + eb-scale: src [48][2048][64] -> dst [48][64][2048],
// dst[.][d][n] = src[.][n][d] * eb[b][n]   (bias folded into V)
__global__ __launch_bounds__(256) void tr_bf16_head(const unsigned short* __restrict__ src,
                                                    const unsigned short* __restrict__ ebb,
                                                    unsigned short* __restrict__ dst) {
  __shared__ unsigned short t[32][33];
  int tx = threadIdx.x & 31, ty = threadIdx.x >> 5;
  size_t hb = (size_t)blockIdx.z * (2048 * 64);
  int b = blockIdx.z / 12;
  int c0 = blockIdx.x * 32, r0 = blockIdx.y * 32;
#pragma unroll
  for (int i = 0; i < 32; i += 8)
    t[ty + i][tx] = src[hb + (size_t)(r0 + ty + i) * 64 + c0 + tx];
  __syncthreads();
  float eb = bf2f(ebb[b * 2048 + r0 + tx]);
#pragma unroll
  for (int i = 0; i < 32; i += 8)
    dst[hb + (size_t)(c0 + ty + i) * 2048 + r0 + tx] = f2bf(bf2f(t[tx][ty + i]) * eb);
}

// ------------------------------- GEMM --------------------------------------
// C[M,N] = A[M,K] * Bt[N,K]^T, 128x128 tile, BK=64, 4 waves (2x2), m97 structure.
// EPI=0: qkv epilogue (bias, q-scale incl. log2e, scatter to q/k/v [B,H,N,64])
// EPI=1: proj epilogue (bias, fp32 out [M][768])
template <int EPI>
__global__ __launch_bounds__(256, 2) void gemm_bt(
    const unsigned short* __restrict__ A, const unsigned short* __restrict__ Bt,
    const float* __restrict__ bias, float* __restrict__ outf,
    unsigned short* __restrict__ qo, unsigned short* __restrict__ ko,
    unsigned short* __restrict__ vo, int K) {
  __shared__ __align__(16) unsigned short As[128 * 64];
  __shared__ __align__(16) unsigned short Bs[128 * 64];
  const int tid = threadIdx.x;
  const int lane = tid & 63, wid = tid >> 6;
  const int lr = lane & 15, lg = lane >> 4;
  const int bm = blockIdx.x, bn = blockIdx.y;
  const int wr = (wid >> 1) * 64, wc = (wid & 1) * 64;

  const unsigned short* ap[4];
  const unsigned short* bp[4];
  unsigned loff[4];
#pragma unroll
  for (int i = 0; i < 4; ++i) {
    int c = wid * 4 + i;
    int r = c * 8 + (lane >> 3);
    int gs = (lane & 7) ^ (r & 7);
    ap[i] = A + (size_t)(bm * 128 + r) * K + gs * 8;
    bp[i] = Bt + (size_t)(bn * 128 + r) * K + gs * 8;
    loff[i] = (unsigned)c * 1024;
  }

  f32x4 acc[4][4] = {};
  const int nt = K >> 6;
  for (int t = 0; t < nt; ++t) {
#pragma unroll
    for (int i = 0; i < 4; ++i) {
      gload_lds16(ap[i], (char*)As + loff[i]);
      gload_lds16(bp[i], (char*)Bs + loff[i]);
      ap[i] += 64;
      bp[i] += 64;
    }
    __syncthreads();
#pragma unroll
    for (int kkk = 0; kkk < 2; ++kkk) {
      short8 af[4], bf[4];
#pragma unroll
      for (int mf = 0; mf < 4; ++mf) {
        int r = wr + mf * 16 + lr;
        int g = kkk * 4 + lg;
        af[mf] = *(const short8*)((const char*)As + r * 128 + ((g ^ (r & 7)) << 4));
      }
#pragma unroll
      for (int nf = 0; nf < 4; ++nf) {
        int r = wc + nf * 16 + lr;
        int g = kkk * 4 + lg;
        bf[nf] = *(const short8*)((const char*)Bs + r * 128 + ((g ^ (r & 7)) << 4));
      }
#pragma unroll
      for (int mf = 0; mf < 4; ++mf)
#pragma unroll
        for (int nf = 0; nf < 4; ++nf)
          acc[mf][nf] = mfma16(af[mf], bf[nf], acc[mf][nf]);
    }
    __syncthreads();
  }

  const int colbase = bn * 128 + wc;
  float bv[4];
#pragma unroll
  for (int nf = 0; nf < 4; ++nf) bv[nf] = bias[colbase + nf * 16 + lr];

  if constexpr (EPI == 0) {
#pragma unroll
    for (int nf = 0; nf < 4; ++nf) {
      int col = colbase + nf * 16 + lr;
      int which = col / 768;
      int rem = col - which * 768;
      int h = rem >> 6, d = rem & 63;
#pragma unroll
      for (int mf = 0; mf < 4; ++mf) {
#pragma unroll
        for (int j = 0; j < 4; ++j) {
          int row = bm * 128 + wr + mf * 16 + lg * 4 + j;
          int bb = row >> 11, nn = row & 2047;
          float v = acc[mf][nf][j] + bv[nf];
          size_t off = (((size_t)bb * 12 + h) * 2048 + nn) * 64 + d;
          if (which == 0)
            qo[off] = f2bf(v * (0.125f * LOG2E));  // fold 1/sqrt(64) and log2e into Q
          else if (which == 1)
            ko[off] = f2bf(v);
          else
            vo[off] = f2bf(v);
        }
      }
    }
  } else {
#pragma unroll
    for (int mf = 0; mf < 4; ++mf) {
#pragma unroll
      for (int j = 0; j < 4; ++j) {
        int row = bm * 128 + wr + mf * 16 + lg * 4 + j;
#pragma unroll
        for (int nf = 0; nf < 4; ++nf) {
          int col = colbase + nf * 16 + lr;
          outf[(size_t)row * 768 + col] = acc[mf][nf][j] + bv[nf];
        }
      }
    }
  }
}

// --------------------------- flash attention -------------------------------
// grid (16 qblocks, 48 heads), 256 thr. Per block: 128 q-rows, 4 waves x 32 rows.
// BARRIER-FREE, LDS-FREE: K fragments read from global with kappa1 applied by
// direct row addressing; V (eb-prescaled, transposed) and eb read from global.
// Each fragment load consumes full 128B rows across its kkk-pair (L2-clean).
// Swapped QK^T -> in-register P pack (kappa1); l via MFMA against eb.
__global__ __launch_bounds__(256, 3) void attn_fused(
    const unsigned short* __restrict__ Q, const unsigned short* __restrict__ Kx,
    const unsigned short* __restrict__ Vt, const unsigned short* __restrict__ ebb,
    unsigned short* __restrict__ Ao) {
  const int tid = threadIdx.x, lane = tid & 63, wid = tid >> 6;
  const int lr = lane & 15, lg = lane >> 4;
  const int qb = blockIdx.x, bh = blockIdx.y;
  const int b = bh / 12, h = bh - b * 12;
  const size_t hoff = (size_t)bh * (2048 * 64);
  const unsigned short* Qh = Q + hoff;
  const unsigned short* Kh = Kx + hoff;
  const unsigned short* Vh = Vt + hoff;        // [64][2048], pre-scaled by eb
  const unsigned short* ebh = ebb + b * 2048;  // bf16 exp(bias), natural order

  // Q fragments (held whole kernel)
  short8 qf[2][2];
#pragma unroll
  for (int mf = 0; mf < 2; ++mf)
#pragma unroll
    for (int kkk = 0; kkk < 2; ++kkk) {
      int qr = qb * 128 + wid * 32 + mf * 16 + lr;
      qf[mf][kkk] = *(const short8*)(Qh + (size_t)qr * 64 + kkk * 32 + lg * 8);
    }

  // kappa1 applied by addressing: S^T slot m = nf*16+lr holds key
  // krow[nf] = 32*(nf&1) + 4*(nf>>1) + 8*(lr>>2) + (lr&3)   (per-lane const)
  const unsigned short* kp[4];
  const unsigned short* vp[4];
#pragma unroll
  for (int nf = 0; nf < 4; ++nf) {
    int krow = 32 * (nf & 1) + 4 * (nf >> 1) + 8 * (lr >> 2) + (lr & 3);
    kp[nf] = Kh + (size_t)krow * 64 + lg * 8;          // advance by 64*64/tile
    vp[nf] = Vh + (size_t)(nf * 16 + lr) * 2048 + lg * 8;  // advance by 64/tile
  }

  f32x4 o[2][4] = {};
  f32x4 ol[2] = {};  // l accumulator via MFMA (all cols identical)

  for (int t = 0; t < 32; ++t) {
    const int kt0 = t * 64;

    // K fragments (slot-permuted rows, direct from global/L1/L2)
    short8 kf[4][2];
#pragma unroll
    for (int nf = 0; nf < 4; ++nf)
#pragma unroll
      for (int kkk = 0; kkk < 2; ++kkk)
        kf[nf][kkk] = *(const short8*)(kp[nf] + (size_t)kt0 * 64 + kkk * 32);

    // V + eb fragments (natural order)
    short8 vr[4][2];
#pragma unroll
    for (int nf = 0; nf < 4; ++nf)
#pragma unroll
      for (int kkk = 0; kkk < 2; ++kkk)
        vr[nf][kkk] = *(const short8*)(vp[nf] + kt0 + kkk * 32);
    short8 ebf[2];
#pragma unroll
    for (int kkk = 0; kkk < 2; ++kkk)
      ebf[kkk] = *(const short8*)(ebh + kt0 + kkk * 32 + lg * 8);

    // S^T = K_slot Q^T : s[nf][mf]
    f32x4 s[4][2] = {};
#pragma unroll
    for (int kkk = 0; kkk < 2; ++kkk)
#pragma unroll
      for (int nf = 0; nf < 4; ++nf)
#pragma unroll
        for (int mf = 0; mf < 2; ++mf)
          s[nf][mf] = mfma16(kf[nf][kkk], qf[mf][kkk], s[nf][mf]);

    // p = exp2(s); shift-free; bias lives in V/eb
#pragma unroll
    for (int nf = 0; nf < 4; ++nf)
#pragma unroll
      for (int mf = 0; mf < 2; ++mf)
#pragma unroll
        for (int j = 0; j < 4; ++j)
          s[nf][mf][j] = __builtin_exp2f(s[nf][mf][j]);

    // pack PV A-fragments in-register (kappa1 lines the slots up)
    short8 pa[2][2];
#pragma unroll
    for (int mf = 0; mf < 2; ++mf)
#pragma unroll
      for (int kkk = 0; kkk < 2; ++kkk) {
        u32x4 w;
        w[0] = cvt_pk_bf16(s[kkk][mf][0], s[kkk][mf][1]);
        w[1] = cvt_pk_bf16(s[kkk][mf][2], s[kkk][mf][3]);
        w[2] = cvt_pk_bf16(s[kkk + 2][mf][0], s[kkk + 2][mf][1]);
        w[3] = cvt_pk_bf16(s[kkk + 2][mf][2], s[kkk + 2][mf][3]);
        pa[mf][kkk] = __builtin_bit_cast(short8, w);
      }

    // O += P (eb*V) ; l += P @ eb
#pragma unroll
    for (int kkk = 0; kkk < 2; ++kkk)
#pragma unroll
      for (int mf = 0; mf < 2; ++mf) {
        ol[mf] = mfma16(pa[mf][kkk], ebf[kkk], ol[mf]);
#pragma unroll
        for (int nf = 0; nf < 4; ++nf)
          o[mf][nf] = mfma16(pa[mf][kkk], vr[nf][kkk], o[mf][nf]);
      }
  }

  // epilogue: O / l -> bf16 -> attn_out [B][N][C]; l is in O-frag layout.
#pragma unroll
  for (int mf = 0; mf < 2; ++mf)
#pragma unroll
    for (int j = 0; j < 4; ++j) {
      float inv = 1.f / ol[mf][j];
      int qr = qb * 128 + wid * 32 + mf * 16 + lg * 4 + j;
#pragma unroll
      for (int nf = 0; nf < 4; ++nf) {
        int d = nf * 16 + lr;
        Ao[((size_t)b * 2048 + qr) * 768 + h * 64 + d] = f2bf(o[mf][nf][j] * inv);
      }
    }
}

// ------------------------------ launcher -----------------------------------

extern "C" void kernel_launch(void* const* d_in, const int* in_sizes, int n_in,
                              void* d_out, int out_size, void* d_ws, size_t ws_size,
                              hipStream_t stream) {
  (void)in_sizes; (void)n_in; (void)out_size; (void)ws_size;
  const float* x = (const float*)d_in[0];
  const float* wqkv = (const float*)d_in[1];
  const float* bqkv = (const float*)d_in[2];
  const float* wproj = (const float*)d_in[3];
  const float* bproj = (const float*)d_in[4];
  const float* klb = (const float*)d_in[5];
  float* out = (float*)d_out;
  char* ws = (char*)d_ws;

  const size_t SZ = (size_t)8192 * 768 * 2;  // 12,582,912 B (one [B,N,C] bf16)
  unsigned short* xb = (unsigned short*)(ws);
  unsigned short* wqkvT = (unsigned short*)(ws + SZ);
  unsigned short* wprojT = (unsigned short*)(ws + SZ + 3538944);
  unsigned short* qbuf = (unsigned short*)(ws + SZ + 3538944 + 1179648);
  unsigned short* kbuf = (unsigned short*)(ws + SZ + 3538944 + 1179648 + SZ);
  unsigned short* vbuf = (unsigned short*)(ws + SZ + 3538944 + 1179648 + 2 * SZ);
  unsigned short* vtbuf = (unsigned short*)(ws + SZ + 3538944 + 1179648 + 3 * SZ);
  unsigned short* ebb = (unsigned short*)(ws + SZ + 3538944 + 1179648 + 4 * SZ);
  unsigned short* aob = xb;  // xb dead after gemm1; reuse for attention output

  cvt_f32_bf16<<<dim3(3072), dim3(256), 0, stream>>>(x, xb, 786432);
  exp_bias<<<dim3(32), dim3(256), 0, stream>>>(klb, ebb, 8192);
  tr_cvt_f32_bf16<<<dim3(72, 24), dim3(256), 0, stream>>>(wqkv, wqkvT, 768, 2304);
  tr_cvt_f32_bf16<<<dim3(24, 24), dim3(256), 0, stream>>>(wproj, wprojT, 768, 768);
  gemm_bt<0><<<dim3(64, 18), dim3(256), 0, stream>>>(xb, wqkvT, bqkv, nullptr,
                                                     qbuf, kbuf, vbuf, 768);
  tr_bf16_head<<<dim3(2, 64, 48), dim3(256), 0, stream>>>(vbuf, ebb, vtbuf);
  attn_fused<<<dim3(16, 48), dim3(256), 0, stream>>>(qbuf, kbuf, vtbuf, ebb, aob);
  gemm_bt<1><<<dim3(64, 6), dim3(256), 0, stream>>>(aob, wprojT, bproj, out,
                                                    nullptr, nullptr, nullptr, 768);
}

// Round 10
// 155.731 us; speedup vs baseline: 1.9727x; 1.6595x over previous
//
#include <hip/hip_runtime.h>

// ---------------------------------------------------------------------------
// Fused attention block: qkv = x@Wqkv+b; per-head softmax(q k^T/8 + keybias) v;
// out = attn@Wproj+b.  B=4 N=2048 C=768 H=12 HD=64.
// Internal compute bf16 MFMA (16x16x32), fp32 accumulate.
// R10: R7 EXACTLY (best known: attn 91us) + KV-loop unrolled x2 so the dbuf
// index is a compile-time literal (ds_read address folding; no per-tile
// address VALU) + hoisted swizzled LDS read offsets.
// Keeps: swapped QK^T + kappa1 in-register P, eb-folded bias, shift-free
// softmax, K/V LDS dbuf w/ 1 barrier/iter, no setprio.
// ---------------------------------------------------------------------------

typedef short short8 __attribute__((ext_vector_type(8)));
typedef float f32x4 __attribute__((ext_vector_type(4)));
typedef unsigned int u32x4 __attribute__((ext_vector_type(4)));

#define GLB_AS(p) ((const __attribute__((address_space(1))) void*)(p))
#define LDS_AS(p) ((__attribute__((address_space(3))) void*)(p))

__device__ __forceinline__ void gload_lds16(const void* g, void* l) {
  // dest = wave-uniform LDS base + lane*16 (m97 fast path)
  __builtin_amdgcn_global_load_lds(GLB_AS(g), LDS_AS(l), 16, 0, 0);
}

__device__ __forceinline__ f32x4 mfma16(short8 a, short8 b, f32x4 c) {
  return __builtin_amdgcn_mfma_f32_16x16x32_bf16(a, b, c, 0, 0, 0);
}

__device__ __forceinline__ unsigned short f2bf(float f) {
  union { float f; unsigned u; } v; v.f = f;
  unsigned r = v.u + 0x7fffu + ((v.u >> 16) & 1u);
  return (unsigned short)(r >> 16);
}

__device__ __forceinline__ float bf2f(unsigned short u) {
  union { unsigned u; float f; } v; v.u = ((unsigned)u) << 16;
  return v.f;
}

// packed f32x2 -> bf16x2 (lo = a, hi = b)
__device__ __forceinline__ unsigned cvt_pk_bf16(float a, float b) {
  unsigned r;
  asm("v_cvt_pk_bf16_f32 %0, %1, %2" : "=v"(r) : "v"(a), "v"(b));
  return r;
}

#define LOG2E 1.44269504088896340736f

// key-slot permutation: S^T slot m holds original key kappa1(m).
// kappa1(m) = 32*m4 + 8*((m>>2)&3) + 4*m5 + (m&3)  (bijective on 0..63)
__device__ __forceinline__ int kappa1(int m) {
  return ((m >> 4) & 1) * 32 + ((m >> 2) & 3) * 8 + ((m >> 5) & 1) * 4 + (m & 3);
}

// --------------------------- pre-pass kernels ------------------------------

__global__ __launch_bounds__(256) void cvt_f32_bf16(const float* __restrict__ in,
                                                    unsigned short* __restrict__ out,
                                                    int n8) {
  int i = blockIdx.x * 256 + threadIdx.x;
  if (i >= n8) return;
  const float4* p = (const float4*)in + 2 * (size_t)i;
  float4 a = p[0], c = p[1];
  short8 r;
  r[0] = (short)f2bf(a.x); r[1] = (short)f2bf(a.y); r[2] = (short)f2bf(a.z); r[3] = (short)f2bf(a.w);
  r[4] = (short)f2bf(c.x); r[5] = (short)f2bf(c.y); r[6] = (short)f2bf(c.z); r[7] = (short)f2bf(c.w);
  ((short8*)out)[i] = r;
}

// ebb[i] = bf16(exp(klb[i]))  (natural key order)
__global__ __launch_bounds__(256) void exp_bias(const float* __restrict__ in,
                                                unsigned short* __restrict__ out, int n) {
  int i = blockIdx.x * 256 + threadIdx.x;
  if (i < n) out[i] = f2bf(__builtin_exp2f(in[i] * LOG2E));
}

// transpose + convert: src fp32 [R][C] -> dst bf16 [C][R]
__global__ __launch_bounds__(256) void tr_cvt_f32_bf16(const float* __restrict__ src,
                                                       unsigned short* __restrict__ dst,
                                                       int R, int C) {
  __shared__ float t[32][33];
  int tx = threadIdx.x & 31, ty = threadIdx.x >> 5;
  int c0 = blockIdx.x * 32, r0 = blockIdx.y * 32;
#pragma unroll
  for (int i = 0; i < 32; i += 8)
    t[ty + i][tx] = src[(size_t)(r0 + ty + i) * C + c0 + tx];
  __syncthreads();
#pragma unroll
  for (int i = 0; i < 32; i += 8)
    dst[(size_t)(c0 + ty + i) * R + r0 + tx] = f2bf(t[tx][ty + i]);
}

// per-head bf16 transpose + eb-scale: src [48][2048][64] -> dst [48][64][2048],
// dst[.][d][n] = src[.][n][d] * eb[b][n]   (bias folded into V)
__global__ __launch_bounds__(256) void tr_bf16_head(const unsigned short* __restrict__ src,
                                                    const unsigned short* __restrict__ ebb,
                                                    unsigned short* __restrict__ dst) {
  __shared__ unsigned short t[32][33];
  int tx = threadIdx.x & 31, ty = threadIdx.x >> 5;
  size_t hb = (size_t)blockIdx.z * (2048 * 64);
  int b = blockIdx.z / 12;
  int c0 = blockIdx.x * 32, r0 = blockIdx.y * 32;
#pragma unroll
  for (int i = 0; i < 32; i += 8)
    t[ty + i][tx] = src[hb + (size_t)(r0 + ty + i) * 64 + c0 + tx];
  __syncthreads();
  float eb = bf2f(ebb[b * 2048 + r0 + tx]);
#pragma unroll
  for (int i = 0; i < 32; i += 8)
    dst[hb + (size_t)(c0 + ty + i) * 2048 + r0 + tx] = f2bf(bf2f(t[tx][ty + i]) * eb);
}

// ------------------------------- GEMM --------------------------------------
// C[M,N] = A[M,K] * Bt[N,K]^T, 128x128 tile, BK=64, 4 waves (2x2), m97 structure.
// EPI=0: qkv epilogue (bias, q-scale incl. log2e, scatter to q/k/v [B,H,N,64])
// EPI=1: proj epilogue (bias, fp32 out [M][768])
template <int EPI>
__global__ __launch_bounds__(256, 2) void gemm_bt(
    const unsigned short* __restrict__ A, const unsigned short* __restrict__ Bt,
    const float* __restrict__ bias, float* __restrict__ outf,
    unsigned short* __restrict__ qo, unsigned short* __restrict__ ko,
    unsigned short* __restrict__ vo, int K) {
  __shared__ __align__(16) unsigned short As[128 * 64];
  __shared__ __align__(16) unsigned short Bs[128 * 64];
  const int tid = threadIdx.x;
  const int lane = tid & 63, wid = tid >> 6;
  const int lr = lane & 15, lg = lane >> 4;
  const int bm = blockIdx.x, bn = blockIdx.y;
  const int wr = (wid >> 1) * 64, wc = (wid & 1) * 64;

  const unsigned short* ap[4];
  const unsigned short* bp[4];
  unsigned loff[4];
#pragma unroll
  for (int i = 0; i < 4; ++i) {
    int c = wid * 4 + i;
    int r = c * 8 + (lane >> 3);
    int gs = (lane & 7) ^ (r & 7);
    ap[i] = A + (size_t)(bm * 128 + r) * K + gs * 8;
    bp[i] = Bt + (size_t)(bn * 128 + r) * K + gs * 8;
    loff[i] = (unsigned)c * 1024;
  }

  f32x4 acc[4][4] = {};
  const int nt = K >> 6;
  for (int t = 0; t < nt; ++t) {
#pragma unroll
    for (int i = 0; i < 4; ++i) {
      gload_lds16(ap[i], (char*)As + loff[i]);
      gload_lds16(bp[i], (char*)Bs + loff[i]);
      ap[i] += 64;
      bp[i] += 64;
    }
    __syncthreads();
#pragma unroll
    for (int kkk = 0; kkk < 2; ++kkk) {
      short8 af[4], bf[4];
#pragma unroll
      for (int mf = 0; mf < 4; ++mf) {
        int r = wr + mf * 16 + lr;
        int g = kkk * 4 + lg;
        af[mf] = *(const short8*)((const char*)As + r * 128 + ((g ^ (r & 7)) << 4));
      }
#pragma unroll
      for (int nf = 0; nf < 4; ++nf) {
        int r = wc + nf * 16 + lr;
        int g = kkk * 4 + lg;
        bf[nf] = *(const short8*)((const char*)Bs + r * 128 + ((g ^ (r & 7)) << 4));
      }
#pragma unroll
      for (int mf = 0; mf < 4; ++mf)
#pragma unroll
        for (int nf = 0; nf < 4; ++nf)
          acc[mf][nf] = mfma16(af[mf], bf[nf], acc[mf][nf]);
    }
    __syncthreads();
  }

  const int colbase = bn * 128 + wc;
  float bv[4];
#pragma unroll
  for (int nf = 0; nf < 4; ++nf) bv[nf] = bias[colbase + nf * 16 + lr];

  if constexpr (EPI == 0) {
#pragma unroll
    for (int nf = 0; nf < 4; ++nf) {
      int col = colbase + nf * 16 + lr;
      int which = col / 768;
      int rem = col - which * 768;
      int h = rem >> 6, d = rem & 63;
#pragma unroll
      for (int mf = 0; mf < 4; ++mf) {
#pragma unroll
        for (int j = 0; j < 4; ++j) {
          int row = bm * 128 + wr + mf * 16 + lg * 4 + j;
          int bb = row >> 11, nn = row & 2047;
          float v = acc[mf][nf][j] + bv[nf];
          size_t off = (((size_t)bb * 12 + h) * 2048 + nn) * 64 + d;
          if (which == 0)
            qo[off] = f2bf(v * (0.125f * LOG2E));  // fold 1/sqrt(64) and log2e into Q
          else if (which == 1)
            ko[off] = f2bf(v);
          else
            vo[off] = f2bf(v);
        }
      }
    }
  } else {
#pragma unroll
    for (int mf = 0; mf < 4; ++mf) {
#pragma unroll
      for (int j = 0; j < 4; ++j) {
        int row = bm * 128 + wr + mf * 16 + lg * 4 + j;
#pragma unroll
        for (int nf = 0; nf < 4; ++nf) {
          int col = colbase + nf * 16 + lr;
          outf[(size_t)row * 768 + col] = acc[mf][nf][j] + bv[nf];
        }
      }
    }
  }
}

// --------------------------- flash attention -------------------------------
// grid (16 qblocks, 48 heads), 256 thr. Per block: 128 q-rows, 4 waves x 32 rows.
// Swapped QK^T (S^T = mfma(K_slot, Q)), kappa1 key permutation -> PV A-frag
// packed in-register (no P LDS). Bias folded into V/eb. K/V LDS dbuf,
// 1 barrier/iter; loop unrolled x2 (compile-time buffer index -> ds_read
// address folding); swizzled read offsets hoisted.
__global__ __launch_bounds__(256, 3) void attn_fused(
    const unsigned short* __restrict__ Q, const unsigned short* __restrict__ Kx,
    const unsigned short* __restrict__ Vt, const unsigned short* __restrict__ ebb,
    unsigned short* __restrict__ Ao) {
  __shared__ __align__(16) unsigned short Ks[2][64 * 64];
  __shared__ __align__(16) unsigned short Vs[2][64 * 64];
  const int tid = threadIdx.x, lane = tid & 63, wid = tid >> 6;
  const int lr = lane & 15, lg = lane >> 4;
  const int qb = blockIdx.x, bh = blockIdx.y;
  const int b = bh / 12, h = bh - b * 12;
  const size_t hoff = (size_t)bh * (2048 * 64);
  const unsigned short* Qh = Q + hoff;
  const unsigned short* Kh = Kx + hoff;
  const unsigned short* Vh = Vt + hoff;        // [64][2048], pre-scaled by eb
  const unsigned short* ebh = ebb + b * 2048;  // bf16 exp(bias), natural order

  // Q fragments (held whole kernel)
  short8 qf[2][2];
#pragma unroll
  for (int mf = 0; mf < 2; ++mf)
#pragma unroll
    for (int kkk = 0; kkk < 2; ++kkk) {
      int qr = qb * 128 + wid * 32 + mf * 16 + lr;
      qf[mf][kkk] = *(const short8*)(Qh + (size_t)qr * 64 + kkk * 32 + lg * 8);
    }

  const int c0 = wid * 2, c1 = wid * 2 + 1;
  const int r0s = c0 * 8 + (lane >> 3), r1s = c1 * 8 + (lane >> 3);
  const int g0 = (lane & 7) ^ (r0s & 7), g1 = (lane & 7) ^ (r1s & 7);
  const int k1r0 = kappa1(r0s), k1r1 = kappa1(r1s);  // K source-row permutation

  // hoisted swizzled LDS read byte-offsets (loop-invariant)
  unsigned koff[2][4], voff[2][4];
#pragma unroll
  for (int kkk = 0; kkk < 2; ++kkk)
#pragma unroll
    for (int nf = 0; nf < 4; ++nf) {
      int r = nf * 16 + lr, g = kkk * 4 + lg;
      koff[kkk][nf] = (unsigned)(r * 128 + ((g ^ (r & 7)) << 4));
      voff[kkk][nf] = koff[kkk][nf];
    }

  f32x4 o[2][4] = {};
  f32x4 ol[2] = {};  // l accumulator via MFMA (all cols identical)

#define STAGE(buf, t)                                                                  \
  do {                                                                                 \
    const int kt0_ = (t) * 64;                                                         \
    gload_lds16(Kh + (size_t)(kt0_ + k1r0) * 64 + g0 * 8, (char*)Ks[buf] + c0 * 1024); \
    gload_lds16(Kh + (size_t)(kt0_ + k1r1) * 64 + g1 * 8, (char*)Ks[buf] + c1 * 1024); \
    gload_lds16(Vh + (size_t)r0s * 2048 + kt0_ + g0 * 8, (char*)Vs[buf] + c0 * 1024);  \
    gload_lds16(Vh + (size_t)r1s * 2048 + kt0_ + g1 * 8, (char*)Vs[buf] + c1 * 1024);  \
  } while (0)

  // BODY(buf, kt0): buf is a literal -> all LDS addresses fold to offset imms
#define BODY(buf, kt0)                                                                 \
  do {                                                                                 \
    short8 ebf[2];                                                                     \
    _Pragma("unroll") for (int kkk = 0; kkk < 2; ++kkk)                                \
        ebf[kkk] = *(const short8*)(ebh + (kt0) + kkk * 32 + lg * 8);                  \
    f32x4 s[4][2] = {};                                                                \
    _Pragma("unroll") for (int kkk = 0; kkk < 2; ++kkk) {                              \
      short8 kf[4];                                                                    \
      _Pragma("unroll") for (int nf = 0; nf < 4; ++nf)                                 \
          kf[nf] = *(const short8*)((const char*)Ks[buf] + koff[kkk][nf]);             \
      _Pragma("unroll") for (int nf = 0; nf < 4; ++nf)                                 \
          _Pragma("unroll") for (int mf = 0; mf < 2; ++mf)                             \
              s[nf][mf] = mfma16(kf[nf], qf[mf][kkk], s[nf][mf]);                      \
    }                                                                                  \
    _Pragma("unroll") for (int nf = 0; nf < 4; ++nf)                                   \
        _Pragma("unroll") for (int mf = 0; mf < 2; ++mf)                               \
            _Pragma("unroll") for (int j = 0; j < 4; ++j)                              \
                s[nf][mf][j] = __builtin_exp2f(s[nf][mf][j]);                          \
    short8 pa[2][2];                                                                   \
    _Pragma("unroll") for (int mf = 0; mf < 2; ++mf)                                   \
        _Pragma("unroll") for (int kkk = 0; kkk < 2; ++kkk) {                          \
      u32x4 w;                                                                         \
      w[0] = cvt_pk_bf16(s[kkk][mf][0], s[kkk][mf][1]);                                \
      w[1] = cvt_pk_bf16(s[kkk][mf][2], s[kkk][mf][3]);                                \
      w[2] = cvt_pk_bf16(s[kkk + 2][mf][0], s[kkk + 2][mf][1]);                        \
      w[3] = cvt_pk_bf16(s[kkk + 2][mf][2], s[kkk + 2][mf][3]);                        \
      pa[mf][kkk] = __builtin_bit_cast(short8, w);                                     \
    }                                                                                  \
    _Pragma("unroll") for (int kkk = 0; kkk < 2; ++kkk) {                              \
      short8 vf[4];                                                                    \
      _Pragma("unroll") for (int nf = 0; nf < 4; ++nf)                                 \
          vf[nf] = *(const short8*)((const char*)Vs[buf] + voff[kkk][nf]);             \
      _Pragma("unroll") for (int mf = 0; mf < 2; ++mf) {                               \
        ol[mf] = mfma16(pa[mf][kkk], ebf[kkk], ol[mf]);                                \
        _Pragma("unroll") for (int nf = 0; nf < 4; ++nf)                               \
            o[mf][nf] = mfma16(pa[mf][kkk], vf[nf], o[mf][nf]);                        \
      }                                                                                \
    }                                                                                  \
  } while (0)

  STAGE(0, 0);

  for (int t = 0; t < 32; t += 2) {
    __syncthreads();  // K/V[0] landed (staged a full phase ago); [1] free
    STAGE(1, t + 1);
    BODY(0, t * 64);
    __syncthreads();  // K/V[1] landed; [0] free
    if (t + 2 < 32) STAGE(0, t + 2);
    BODY(1, (t + 1) * 64);
  }
#undef STAGE
#undef BODY

  // epilogue: O / l -> bf16 -> attn_out [B][N][C]; l is in O-frag layout.
#pragma unroll
  for (int mf = 0; mf < 2; ++mf)
#pragma unroll
    for (int j = 0; j < 4; ++j) {
      float inv = 1.f / ol[mf][j];
      int qr = qb * 128 + wid * 32 + mf * 16 + lg * 4 + j;
#pragma unroll
      for (int nf = 0; nf < 4; ++nf) {
        int d = nf * 16 + lr;
        Ao[((size_t)b * 2048 + qr) * 768 + h * 64 + d] = f2bf(o[mf][nf][j] * inv);
      }
    }
}

// ------------------------------ launcher -----------------------------------

extern "C" void kernel_launch(void* const* d_in, const int* in_sizes, int n_in,
                              void* d_out, int out_size, void* d_ws, size_t ws_size,
                              hipStream_t stream) {
  (void)in_sizes; (void)n_in; (void)out_size; (void)ws_size;
  const float* x = (const float*)d_in[0];
  const float* wqkv = (const float*)d_in[1];
  const float* bqkv = (const float*)d_in[2];
  const float* wproj = (const float*)d_in[3];
  const float* bproj = (const float*)d_in[4];
  const float* klb = (const float*)d_in[5];
  float* out = (float*)d_out;
  char* ws = (char*)d_ws;

  const size_t SZ = (size_t)8192 * 768 * 2;  // 12,582,912 B (one [B,N,C] bf16)
  unsigned short* xb = (unsigned short*)(ws);
  unsigned short* wqkvT = (unsigned short*)(ws + SZ);
  unsigned short* wprojT = (unsigned short*)(ws + SZ + 3538944);
  unsigned short* qbuf = (unsigned short*)(ws + SZ + 3538944 + 1179648);
  unsigned short* kbuf = (unsigned short*)(ws + SZ + 3538944 + 1179648 + SZ);
  unsigned short* vbuf = (unsigned short*)(ws + SZ + 3538944 + 1179648 + 2 * SZ);
  unsigned short* vtbuf = (unsigned short*)(ws + SZ + 3538944 + 1179648 + 3 * SZ);
  unsigned short* ebb = (unsigned short*)(ws + SZ + 3538944 + 1179648 + 4 * SZ);
  unsigned short* aob = xb;  // xb dead after gemm1; reuse for attention output

  cvt_f32_bf16<<<dim3(3072), dim3(256), 0, stream>>>(x, xb, 786432);
  exp_bias<<<dim3(32), dim3(256), 0, stream>>>(klb, ebb, 8192);
  tr_cvt_f32_bf16<<<dim3(72, 24), dim3(256), 0, stream>>>(wqkv, wqkvT, 768, 2304);
  tr_cvt_f32_bf16<<<dim3(24, 24), dim3(256), 0, stream>>>(wproj, wprojT, 768, 768);
  gemm_bt<0><<<dim3(64, 18), dim3(256), 0, stream>>>(xb, wqkvT, bqkv, nullptr,
                                                     qbuf, kbuf, vbuf, 768);
  tr_bf16_head<<<dim3(2, 64, 48), dim3(256), 0, stream>>>(vbuf, ebb, vtbuf);
  attn_fused<<<dim3(16, 48), dim3(256), 0, stream>>>(qbuf, kbuf, vtbuf, ebb, aob);
  gemm_bt<1><<<dim3(64, 6), dim3(256), 0, stream>>>(aob, wprojT, bproj, out,
                                                    nullptr, nullptr, nullptr, 768);
}